// Round 6
// baseline (1562.337 us; speedup 1.0000x reference)
//
#include <hip/hip_runtime.h>

// ODENet: y_{t+1} = y_t + f(x_t, y_t),  f = W3^T tanh(W2^T tanh(x*W1[0] + y*W1[1] + b1) + b2) + b3
// out[t][b] = y_t (pre-update state).  SEQ=2048 sequential steps, BATCH=512 independent chains.
//
// Round-6: 512 WGs x 256 threads, ONE chain per WG (M=1), __launch_bounds__(256,2) so TWO
// independent WGs co-reside per CU (2 waves/SIMD). Each WG's serial spine (barriers, LDS
// roundtrips, fold, h1) hides under the other WG's MFMA bursts — the ~1070 cyc of
// non-MFMA step time measured in rounds 1-3 overlaps instead of being exposed.
// All cross-lane tricks reverted to round-3-verified patterns (DPP row16 reduce only).

#define SEQ 2048
#define BATCH 512
#define HID 256

typedef __bf16 bf16x8 __attribute__((ext_vector_type(8)));
typedef short short8 __attribute__((ext_vector_type(8)));
typedef float f32x4 __attribute__((ext_vector_type(4)));

__device__ __forceinline__ unsigned short f2bf_rne(float f) {
  unsigned u = __builtin_bit_cast(unsigned, f);
  u += 0x7fffu + ((u >> 16) & 1u);
  return (unsigned short)(u >> 16);
}

// Padé [7/6] tanh, clamp +-4.5; max abs err ~6.5e-4.
__device__ __forceinline__ float tanh_pade(float x) {
  float cx = __builtin_amdgcn_fmed3f(x, -4.5f, 4.5f);
  float u = cx * cx;
  float num = cx * (10395.f + u * (1260.f + 21.f * u));
  float den = 10395.f + u * (4725.f + u * (210.f + u));
  return num * __builtin_amdgcn_rcpf(den);
}

// Sum over each 16-lane DPP row; valid in lane 15 of the row.
__device__ __forceinline__ float row16_sum_to_lane15(float v) {
  int s;
  s = __builtin_amdgcn_update_dpp(0, __builtin_bit_cast(int, v), 0x111, 0xf, 0xf, true);
  v += __builtin_bit_cast(float, s);
  s = __builtin_amdgcn_update_dpp(0, __builtin_bit_cast(int, v), 0x112, 0xf, 0xf, true);
  v += __builtin_bit_cast(float, s);
  s = __builtin_amdgcn_update_dpp(0, __builtin_bit_cast(int, v), 0x114, 0xf, 0xf, true);
  v += __builtin_bit_cast(float, s);
  s = __builtin_amdgcn_update_dpp(0, __builtin_bit_cast(int, v), 0x118, 0xf, 0xf, true);
  v += __builtin_bit_cast(float, s);
  return v;
}

// Pack W2 (256x256 fp32, row-major [k][c]) into bf16 B-fragments.
// ws[(((tile*8)+kc)*64 + lane)*8 + e] = bf16(W2[k][c]) with
//   k = kc*32 + (lane>>4)*8 + e,  c = tile*16 + (lane&15)
__global__ void pack_w2_kernel(const float* __restrict__ W2,
                               unsigned short* __restrict__ ws) {
  int idx = blockIdx.x * 256 + threadIdx.x;     // 0..65535
  int e    = idx & 7;
  int l    = (idx >> 3) & 63;
  int kc   = (idx >> 9) & 7;
  int tile = idx >> 12;                         // 0..15
  int k = kc * 32 + (l >> 4) * 8 + e;
  int c = tile * 16 + (l & 15);
  ws[idx] = f2bf_rne(W2[k * HID + c]);
}

__global__ __launch_bounds__(256, 2) void odenet_kernel(
    const float* __restrict__ x, const float* __restrict__ W1,
    const float* __restrict__ b1, const unsigned short* __restrict__ wsW2,
    const float* __restrict__ b2, const float* __restrict__ W3,
    const float* __restrict__ b3, const float* __restrict__ state0,
    float* __restrict__ out) {
  __shared__ __align__(16) unsigned short A_lds[HID]; // h1 bf16, 1 row
  __shared__ __align__(16) float partial[4];          // [wave]

  const int tid  = threadIdx.x;   // 0..255 == column j
  const int lane = tid & 63;
  const int wave = tid >> 6;      // 0..3
  const int j    = tid;
  const int b0   = blockIdx.x;    // one chain per WG

  // --- persistent constants ---
  const float w10 = W1[j];
  const float w11 = W1[HID + j];
  const float b1j = b1[j];
  const float b3v = b3[0];
  float b2c[4], w3c[4];
#pragma unroll
  for (int t = 0; t < 4; ++t) {
    const int c = wave * 64 + t * 16 + (lane & 15);
    b2c[t] = b2[c];
    w3c[t] = W3[c];
  }

  // --- B fragments: wave owns tiles wave*4 .. wave*4+3 (64 columns) ---
  short8 bf[4][8];
  {
    const short8* wp = (const short8*)wsW2;
#pragma unroll
    for (int t = 0; t < 4; ++t)
#pragma unroll
      for (int kc = 0; kc < 8; ++kc)
        bf[t][kc] = wp[((wave * 4 + t) * 8 + kc) * 64 + lane];
  }

  // --- A fragments: only row m=0 (lane&15==0) real; rest zero ---
  const short8 zero8 = {0, 0, 0, 0, 0, 0, 0, 0};
  short8 areg[8];
#pragma unroll
  for (int kc = 0; kc < 8; ++kc) areg[kc] = zero8;
  const bool aread = ((lane & 15) == 0);   // lanes 0,16,32,48
  const int  aoff  = (lane >> 4) * 8;      // ushort index

  const f32x4 kZero = {0.f, 0.f, 0.f, 0.f};

  float y = state0[b0];

  const float* xp = x + b0;
  float* yo = out + b0;

  // x prefetch double buffer (4 steps ahead, scalar)
  float xb[4], xn[4];
#pragma unroll
  for (int i = 0; i < 4; ++i) xb[i] = xp[i * BATCH];

  for (int tb = 0; tb < SEQ; tb += 4) {
    if (tb + 4 < SEQ) {
      const float* xq = xp + (tb + 4) * BATCH;
#pragma unroll
      for (int i = 0; i < 4; ++i) xn[i] = xq[i * BATCH];
    }

#pragma unroll
    for (int i = 0; i < 4; ++i) {
      const int t = tb + i;

      // --- h1[j] = tanh(x*W1[0,j] + y*W1[1,j] + b1[j]) -> LDS (bf16) ---
      const float pre = __builtin_fmaf(y, w11, __builtin_fmaf(xb[i], w10, b1j));
      A_lds[j] = f2bf_rne(tanh_pade(pre));
      __syncthreads(); // bar1: h1 visible

      // --- A-fragments (4 active lanes; pad lanes keep zeros) ---
      if (aread) {
#pragma unroll
        for (int kc = 0; kc < 8; ++kc)
          areg[kc] = *(const short8*)&A_lds[aoff + kc * 32];
      }

      // --- h2 pre-activation: 4 column-tiles, K=256 over 8 chunks ---
      f32x4 acc0, acc1, acc2, acc3;
      {
        const bf16x8 a = __builtin_bit_cast(bf16x8, areg[0]);
        acc0 = __builtin_amdgcn_mfma_f32_16x16x32_bf16(a, __builtin_bit_cast(bf16x8, bf[0][0]), kZero, 0, 0, 0);
        acc1 = __builtin_amdgcn_mfma_f32_16x16x32_bf16(a, __builtin_bit_cast(bf16x8, bf[1][0]), kZero, 0, 0, 0);
        acc2 = __builtin_amdgcn_mfma_f32_16x16x32_bf16(a, __builtin_bit_cast(bf16x8, bf[2][0]), kZero, 0, 0, 0);
        acc3 = __builtin_amdgcn_mfma_f32_16x16x32_bf16(a, __builtin_bit_cast(bf16x8, bf[3][0]), kZero, 0, 0, 0);
      }
#pragma unroll
      for (int kc = 1; kc < 8; ++kc) {
        const bf16x8 a = __builtin_bit_cast(bf16x8, areg[kc]);
        acc0 = __builtin_amdgcn_mfma_f32_16x16x32_bf16(a, __builtin_bit_cast(bf16x8, bf[0][kc]), acc0, 0, 0, 0);
        acc1 = __builtin_amdgcn_mfma_f32_16x16x32_bf16(a, __builtin_bit_cast(bf16x8, bf[1][kc]), acc1, 0, 0, 0);
        acc2 = __builtin_amdgcn_mfma_f32_16x16x32_bf16(a, __builtin_bit_cast(bf16x8, bf[2][kc]), acc2, 0, 0, 0);
        acc3 = __builtin_amdgcn_mfma_f32_16x16x32_bf16(a, __builtin_bit_cast(bf16x8, bf[3][kc]), acc3, 0, 0, 0);
      }

      // --- h2 = tanh(acc+b2), dot W3: chain lives in lanes 0-15, reg0 ---
      float s = 0.f;
      if (lane < 16) {
        s  = tanh_pade(acc0[0] + b2c[0]) * w3c[0];
        s += tanh_pade(acc1[0] + b2c[1]) * w3c[1];
        s += tanh_pade(acc2[0] + b2c[2]) * w3c[2];
        s += tanh_pade(acc3[0] + b2c[3]) * w3c[3];
      }
      s = row16_sum_to_lane15(s);
      if (lane == 15) partial[wave] = s;
      __syncthreads(); // bar2: partials visible

      // --- fold 4 wave-partials; y update (all threads identically) ---
      const f32x4 q = *(const f32x4*)&partial[0];
      const float f = ((q[0] + q[1]) + (q[2] + q[3])) + b3v;
      const float y_old = y;
      y += f; // DT = 1.0
      if (tid == 0) yo[t * BATCH] = y_old; // ys[t] = pre-update state
    }

    if (tb + 4 < SEQ) {
#pragma unroll
      for (int i = 0; i < 4; ++i) xb[i] = xn[i];
    }
  }
}

extern "C" void kernel_launch(void* const* d_in, const int* in_sizes, int n_in,
                              void* d_out, int out_size, void* d_ws, size_t ws_size,
                              hipStream_t stream) {
  const float* x  = (const float*)d_in[0];
  const float* W1 = (const float*)d_in[1];
  const float* b1 = (const float*)d_in[2];
  const float* W2 = (const float*)d_in[3];
  const float* b2 = (const float*)d_in[4];
  const float* W3 = (const float*)d_in[5];
  const float* b3 = (const float*)d_in[6];
  const float* s0 = (const float*)d_in[7];
  unsigned short* ws = (unsigned short*)d_ws; // 65536 bf16 = 128 KB
  float* out = (float*)d_out;

  pack_w2_kernel<<<256, 256, 0, stream>>>(W2, ws);
  odenet_kernel<<<512, 256, 0, stream>>>(x, W1, b1, ws, b2, W3, b3, s0, out);
}

// Round 7
// 1347.974 us; speedup vs baseline: 1.1590x; 1.1590x over previous
//
#include <hip/hip_runtime.h>

// ODENet: y_{t+1} = y_t + f(x_t, y_t),  f = W3^T tanh(W2^T tanh(x*W1[0] + y*W1[1] + b1) + b2) + b3
// out[t][b] = y_t (pre-update state).  SEQ=2048 sequential steps, BATCH=512 independent chains.
//
// Round-7: R3 skeleton (256 WGs x 256 thr, M=2 chains at MFMA rows 0,4; 1 wave/SIMD) with the
// serial spine trimmed:
//  - A-fragment reads UNMASKED with clamped addresses (pad lanes read dup row-0 data; only
//    C rows 0 and 4 are consumed and they depend solely on their own lanes' A rows).
//  - tanh2 UNMASKED on all 64 lanes (garbage confined to lanes 32-63's 16-groups).
//  - tile-pair ordering: tiles{0,1} MFMA chain -> s01 VALU -> tiles{2,3} chain -> s23,
//    so epilogue VALU interleaves with MFMA pipe drain.
//  - acc init via kZero C-operand on kc=0; x*W1[0]+b1 precomputed per 8-step block.
// Cycle model: MFMA floor = 32 MFMA/SIMD/step x 19.4 cyc = 620; spine was ~1070 in R3.

#define SEQ 2048
#define BATCH 512
#define HID 256

typedef __bf16 bf16x8 __attribute__((ext_vector_type(8)));
typedef short short8 __attribute__((ext_vector_type(8)));
typedef float f32x4 __attribute__((ext_vector_type(4)));

__device__ __forceinline__ unsigned short f2bf_rne(float f) {
  unsigned u = __builtin_bit_cast(unsigned, f);
  u += 0x7fffu + ((u >> 16) & 1u);
  return (unsigned short)(u >> 16);
}

// Padé [7/6] tanh, clamp +-4.5; max abs err ~6.5e-4.
__device__ __forceinline__ float tanh_pade(float x) {
  float cx = __builtin_amdgcn_fmed3f(x, -4.5f, 4.5f);
  float u = cx * cx;
  float num = cx * (10395.f + u * (1260.f + 21.f * u));
  float den = 10395.f + u * (4725.f + u * (210.f + u));
  return num * __builtin_amdgcn_rcpf(den);
}

// Sum over each 16-lane DPP row; valid in lane 15 of the row.
__device__ __forceinline__ float row16_sum_to_lane15(float v) {
  int s;
  s = __builtin_amdgcn_update_dpp(0, __builtin_bit_cast(int, v), 0x111, 0xf, 0xf, true);
  v += __builtin_bit_cast(float, s);
  s = __builtin_amdgcn_update_dpp(0, __builtin_bit_cast(int, v), 0x112, 0xf, 0xf, true);
  v += __builtin_bit_cast(float, s);
  s = __builtin_amdgcn_update_dpp(0, __builtin_bit_cast(int, v), 0x114, 0xf, 0xf, true);
  v += __builtin_bit_cast(float, s);
  s = __builtin_amdgcn_update_dpp(0, __builtin_bit_cast(int, v), 0x118, 0xf, 0xf, true);
  v += __builtin_bit_cast(float, s);
  return v;
}

// Pack W2 (256x256 fp32, row-major [k][c]) into bf16 B-fragments.
// ws[(((tile*8)+kc)*64 + lane)*8 + e] = bf16(W2[k][c]) with
//   k = kc*32 + (lane>>4)*8 + e,  c = tile*16 + (lane&15)
__global__ void pack_w2_kernel(const float* __restrict__ W2,
                               unsigned short* __restrict__ ws) {
  int idx = blockIdx.x * 256 + threadIdx.x;     // 0..65535
  int e    = idx & 7;
  int l    = (idx >> 3) & 63;
  int kc   = (idx >> 9) & 7;
  int tile = idx >> 12;                         // 0..15
  int k = kc * 32 + (l >> 4) * 8 + e;
  int c = tile * 16 + (l & 15);
  ws[idx] = f2bf_rne(W2[k * HID + c]);
}

__global__ __launch_bounds__(256, 1) void odenet_kernel(
    const float* __restrict__ x, const float* __restrict__ W1,
    const float* __restrict__ b1, const unsigned short* __restrict__ wsW2,
    const float* __restrict__ b2, const float* __restrict__ W3,
    const float* __restrict__ b3, const float* __restrict__ state0,
    float* __restrict__ out) {
  __shared__ __align__(16) unsigned short A_lds[2 * HID]; // h1 bf16, rows 0..1 (chain0, chain1)
  __shared__ __align__(16) float partial[2][4];           // [chain][wave]

  const int tid  = threadIdx.x;   // 0..255 == column j
  const int lane = tid & 63;
  const int wave = tid >> 6;      // 0..3
  const int j    = tid;
  const int b0   = blockIdx.x * 2;

  // --- persistent constants ---
  const float w10 = W1[j];
  const float w11 = W1[HID + j];
  const float b1j = b1[j];
  const float b3v = b3[0];
  float b2c[4], w3c[4];
#pragma unroll
  for (int t = 0; t < 4; ++t) {
    const int c = wave * 64 + t * 16 + (lane & 15);
    b2c[t] = b2[c];
    w3c[t] = W3[c];
  }

  // --- B fragments: wave owns tiles wave*4 .. wave*4+3 (64 columns) ---
  short8 bf[4][8];
  {
    const short8* wp = (const short8*)wsW2;
#pragma unroll
    for (int t = 0; t < 4; ++t)
#pragma unroll
      for (int kc = 0; kc < 8; ++kc)
        bf[t][kc] = wp[((wave * 4 + t) * 8 + kc) * 64 + lane];
  }

  // --- A-read address, UNMASKED (clamped): lanes with lane&15==0 get row0 (chain0),
  //     lane&15==4 get row1 (chain1); all other (pad) lanes read a duplicate of one of
  //     those rows — harmless, since only C rows 0 and 4 are consumed and each C row
  //     depends only on the A elements held by its own lanes. All addresses in-bounds.
  const int aoff = ((lane >> 2) & 1) * HID + (lane >> 4) * 8; // ushort index

  const f32x4 kZero = {0.f, 0.f, 0.f, 0.f};

  float y0 = state0[b0];
  float y1 = state0[b0 + 1];

  const float* xp = x + b0;
  float* yo = out + b0;

  // x prefetch double buffer (8 steps ahead); xa_r = x_r*W1[0,j] + b1[j]
  float2 xb[8], xn[8];
  float xa0[8], xa1[8];
#pragma unroll
  for (int i = 0; i < 8; ++i) xb[i] = *(const float2*)&xp[i * BATCH];
#pragma unroll
  for (int i = 0; i < 8; ++i) {
    xa0[i] = xb[i].x * w10 + b1j;
    xa1[i] = xb[i].y * w10 + b1j;
  }

  for (int tb = 0; tb < SEQ; tb += 8) {
    if (tb + 8 < SEQ) {
      const float* xq = xp + (tb + 8) * BATCH;
#pragma unroll
      for (int i = 0; i < 8; ++i) xn[i] = *(const float2*)&xq[i * BATCH];
    }

#pragma unroll
    for (int i = 0; i < 8; ++i) {
      const int t = tb + i;

      // --- h1[r][j] = tanh(x_r*W1[0,j] + y_r*W1[1,j] + b1[j]) -> LDS (bf16) ---
      const float pre0 = __builtin_fmaf(y0, w11, xa0[i]);
      const float pre1 = __builtin_fmaf(y1, w11, xa1[i]);
      A_lds[j]       = f2bf_rne(tanh_pade(pre0));
      A_lds[HID + j] = f2bf_rne(tanh_pade(pre1));
      __syncthreads(); // bar1: h1 visible

      // --- A-fragments: unconditional vector reads (broadcast-heavy, conflict-free) ---
      short8 areg[8];
#pragma unroll
      for (int kc = 0; kc < 8; ++kc)
        areg[kc] = *(const short8*)&A_lds[aoff + kc * 32];

      // --- tiles 0,1: K=256 over 8 chunks (2 indep acc chains) ---
      f32x4 acc0, acc1, acc2, acc3;
      {
        const bf16x8 a = __builtin_bit_cast(bf16x8, areg[0]);
        acc0 = __builtin_amdgcn_mfma_f32_16x16x32_bf16(a, __builtin_bit_cast(bf16x8, bf[0][0]), kZero, 0, 0, 0);
        acc1 = __builtin_amdgcn_mfma_f32_16x16x32_bf16(a, __builtin_bit_cast(bf16x8, bf[1][0]), kZero, 0, 0, 0);
      }
#pragma unroll
      for (int kc = 1; kc < 8; ++kc) {
        const bf16x8 a = __builtin_bit_cast(bf16x8, areg[kc]);
        acc0 = __builtin_amdgcn_mfma_f32_16x16x32_bf16(a, __builtin_bit_cast(bf16x8, bf[0][kc]), acc0, 0, 0, 0);
        acc1 = __builtin_amdgcn_mfma_f32_16x16x32_bf16(a, __builtin_bit_cast(bf16x8, bf[1][kc]), acc1, 0, 0, 0);
      }

      // --- s01 on ALL lanes (lanes 32-63 compute confined garbage);
      //     chain0 lives in lanes 0-15 reg0, chain1 in lanes 16-31 reg0 ---
      float s = tanh_pade(acc0[0] + b2c[0]) * w3c[0] +
                tanh_pade(acc1[0] + b2c[1]) * w3c[1];

      // --- tiles 2,3 (VALU above slots into this MFMA issue/drain) ---
      {
        const bf16x8 a = __builtin_bit_cast(bf16x8, areg[0]);
        acc2 = __builtin_amdgcn_mfma_f32_16x16x32_bf16(a, __builtin_bit_cast(bf16x8, bf[2][0]), kZero, 0, 0, 0);
        acc3 = __builtin_amdgcn_mfma_f32_16x16x32_bf16(a, __builtin_bit_cast(bf16x8, bf[3][0]), kZero, 0, 0, 0);
      }
#pragma unroll
      for (int kc = 1; kc < 8; ++kc) {
        const bf16x8 a = __builtin_bit_cast(bf16x8, areg[kc]);
        acc2 = __builtin_amdgcn_mfma_f32_16x16x32_bf16(a, __builtin_bit_cast(bf16x8, bf[2][kc]), acc2, 0, 0, 0);
        acc3 = __builtin_amdgcn_mfma_f32_16x16x32_bf16(a, __builtin_bit_cast(bf16x8, bf[3][kc]), acc3, 0, 0, 0);
      }

      s += tanh_pade(acc2[0] + b2c[2]) * w3c[2] +
           tanh_pade(acc3[0] + b2c[3]) * w3c[3];

      // --- reduce 16-lane column groups; chain0 -> lane15, chain1 -> lane31 ---
      const float r = row16_sum_to_lane15(s);
      if ((lane & 15) == 15 && lane < 32)
        partial[lane >> 4][wave] = r;
      __syncthreads(); // bar2: partials visible

      // --- fold 4 wave-partials per chain; y update (all threads identically) ---
      const f32x4 q0 = *(const f32x4*)&partial[0][0];
      const f32x4 q1 = *(const f32x4*)&partial[1][0];
      const float f0 = ((q0[0] + q0[1]) + (q0[2] + q0[3])) + b3v;
      const float f1 = ((q1[0] + q1[1]) + (q1[2] + q1[3])) + b3v;
      const float y0o = y0, y1o = y1;
      y0 += f0; // DT = 1.0
      y1 += f1;
      if (tid == 0) {
        float2 o{y0o, y1o};
        *(float2*)&yo[t * BATCH] = o; // ys[t] = pre-update state
      }
    }

    if (tb + 8 < SEQ) {
#pragma unroll
      for (int i = 0; i < 8; ++i) xb[i] = xn[i];
#pragma unroll
      for (int i = 0; i < 8; ++i) {
        xa0[i] = xb[i].x * w10 + b1j;
        xa1[i] = xb[i].y * w10 + b1j;
      }
    }
  }
}

extern "C" void kernel_launch(void* const* d_in, const int* in_sizes, int n_in,
                              void* d_out, int out_size, void* d_ws, size_t ws_size,
                              hipStream_t stream) {
  const float* x  = (const float*)d_in[0];
  const float* W1 = (const float*)d_in[1];
  const float* b1 = (const float*)d_in[2];
  const float* W2 = (const float*)d_in[3];
  const float* b2 = (const float*)d_in[4];
  const float* W3 = (const float*)d_in[5];
  const float* b3 = (const float*)d_in[6];
  const float* s0 = (const float*)d_in[7];
  unsigned short* ws = (unsigned short*)d_ws; // 65536 bf16 = 128 KB
  float* out = (float*)d_out;

  pack_w2_kernel<<<256, 256, 0, stream>>>(W2, ws);
  odenet_kernel<<<256, 256, 0, stream>>>(x, W1, b1, ws, b2, W3, b3, s0, out);
}

// Round 8
// 1299.928 us; speedup vs baseline: 1.2019x; 1.0370x over previous
//
#include <hip/hip_runtime.h>

// ODENet: y_{t+1} = y_t + f(x_t, y_t),  f = W3^T tanh(W2^T tanh(x*W1[0] + y*W1[1] + b1) + b2) + b3
// out[t][b] = y_t (pre-update state).  SEQ=2048 sequential steps, BATCH=512 independent chains.
//
// Round-8: R7 skeleton (256 WGs x 256 thr, M=2 chains at MFMA rows 0,4; 1 wave/SIMD), plus:
//  - A_lds row stride padded 256->288 ushorts: row0 hits banks 0-15, row1 banks 16-31 -> the
//    6.7e7 2-way conflicts from R7's unmasked A-reads go to ~0.
//  - fold-at-top: base(t) = xa[t] + w11*y(t-1) is computed during the MFMA phase; the
//    post-bar2 critical path is read->fold->fma->tanh1->pack->write (~175 cyc, was ~240).
//    Step-0 is branch-free: partials pre-initialized to -b3/4 so the first fold gives f=0
//    exactly (pairwise sum of four -b3/4 terms is exact; +b3 cancels).
//  - out[t] stored after fold = pre-update state of step t (matches lax.scan semantics).

#define SEQ 2048
#define BATCH 512
#define HID 256
#define LDA 288  // padded row stride (ushorts); 576 B -> rows land on disjoint bank halves

typedef __bf16 bf16x8 __attribute__((ext_vector_type(8)));
typedef short short8 __attribute__((ext_vector_type(8)));
typedef float f32x4 __attribute__((ext_vector_type(4)));

__device__ __forceinline__ unsigned short f2bf_rne(float f) {
  unsigned u = __builtin_bit_cast(unsigned, f);
  u += 0x7fffu + ((u >> 16) & 1u);
  return (unsigned short)(u >> 16);
}

// Padé [7/6] tanh, clamp +-4.5; max abs err ~6.5e-4.
__device__ __forceinline__ float tanh_pade(float x) {
  float cx = __builtin_amdgcn_fmed3f(x, -4.5f, 4.5f);
  float u = cx * cx;
  float num = cx * (10395.f + u * (1260.f + 21.f * u));
  float den = 10395.f + u * (4725.f + u * (210.f + u));
  return num * __builtin_amdgcn_rcpf(den);
}

// Sum over each 16-lane DPP row; valid in lane 15 of the row.
__device__ __forceinline__ float row16_sum_to_lane15(float v) {
  int s;
  s = __builtin_amdgcn_update_dpp(0, __builtin_bit_cast(int, v), 0x111, 0xf, 0xf, true);
  v += __builtin_bit_cast(float, s);
  s = __builtin_amdgcn_update_dpp(0, __builtin_bit_cast(int, v), 0x112, 0xf, 0xf, true);
  v += __builtin_bit_cast(float, s);
  s = __builtin_amdgcn_update_dpp(0, __builtin_bit_cast(int, v), 0x114, 0xf, 0xf, true);
  v += __builtin_bit_cast(float, s);
  s = __builtin_amdgcn_update_dpp(0, __builtin_bit_cast(int, v), 0x118, 0xf, 0xf, true);
  v += __builtin_bit_cast(float, s);
  return v;
}

// Pack W2 (256x256 fp32, row-major [k][c]) into bf16 B-fragments.
// ws[(((tile*8)+kc)*64 + lane)*8 + e] = bf16(W2[k][c]) with
//   k = kc*32 + (lane>>4)*8 + e,  c = tile*16 + (lane&15)
__global__ void pack_w2_kernel(const float* __restrict__ W2,
                               unsigned short* __restrict__ ws) {
  int idx = blockIdx.x * 256 + threadIdx.x;     // 0..65535
  int e    = idx & 7;
  int l    = (idx >> 3) & 63;
  int kc   = (idx >> 9) & 7;
  int tile = idx >> 12;                         // 0..15
  int k = kc * 32 + (l >> 4) * 8 + e;
  int c = tile * 16 + (l & 15);
  ws[idx] = f2bf_rne(W2[k * HID + c]);
}

__global__ __launch_bounds__(256, 1) void odenet_kernel(
    const float* __restrict__ x, const float* __restrict__ W1,
    const float* __restrict__ b1, const unsigned short* __restrict__ wsW2,
    const float* __restrict__ b2, const float* __restrict__ W3,
    const float* __restrict__ b3, const float* __restrict__ state0,
    float* __restrict__ out) {
  __shared__ __align__(16) unsigned short A_lds[2 * LDA]; // h1 bf16, padded rows
  __shared__ __align__(16) float partial[2][4];           // [chain][wave]

  const int tid  = threadIdx.x;   // 0..255 == column j
  const int lane = tid & 63;
  const int wave = tid >> 6;      // 0..3
  const int j    = tid;
  const int b0   = blockIdx.x * 2;

  // --- persistent constants ---
  const float w10 = W1[j];
  const float w11 = W1[HID + j];
  const float b1j = b1[j];
  const float b3v = b3[0];
  float b2c[4], w3c[4];
#pragma unroll
  for (int t = 0; t < 4; ++t) {
    const int c = wave * 64 + t * 16 + (lane & 15);
    b2c[t] = b2[c];
    w3c[t] = W3[c];
  }

  // --- B fragments: wave owns tiles wave*4 .. wave*4+3 (64 columns) ---
  short8 bf[4][8];
  {
    const short8* wp = (const short8*)wsW2;
#pragma unroll
    for (int t = 0; t < 4; ++t)
#pragma unroll
      for (int kc = 0; kc < 8; ++kc)
        bf[t][kc] = wp[((wave * 4 + t) * 8 + kc) * 64 + lane];
  }

  // --- A-read address, unmasked (pad lanes read duplicate chain rows; only C rows 0,4
  //     are consumed and each depends solely on its own lanes' A values) ---
  const int aoff = ((lane >> 2) & 1) * LDA + (lane >> 4) * 8; // ushort index

  const f32x4 kZero = {0.f, 0.f, 0.f, 0.f};

  float y0 = state0[b0];
  float y1 = state0[b0 + 1];

  const float* xp = x + b0;
  float* yo = out + b0;

  // x prefetch double buffer (8 steps ahead); xa_r = x_r*W1[0,j] + b1[j]
  float2 xb[8], xn[8];
  float xa0[8], xa1[8];
#pragma unroll
  for (int i = 0; i < 8; ++i) xb[i] = *(const float2*)&xp[i * BATCH];
#pragma unroll
  for (int i = 0; i < 8; ++i) {
    xa0[i] = xb[i].x * w10 + b1j;
    xa1[i] = xb[i].y * w10 + b1j;
  }

  // --- prologue: partials init so step-0 fold yields exactly f = 0 ---
  if (tid < 8) ((float*)partial)[tid] = -0.25f * b3v;
  // base(0) = xa[0] + w11*y(init)
  float base0 = __builtin_fmaf(y0, w11, xa0[0]);
  float base1 = __builtin_fmaf(y1, w11, xa1[0]);
  __syncthreads(); // partials visible (acts as the "bar2" preceding step 0)

  for (int tb = 0; tb < SEQ; tb += 8) {
    if (tb + 8 < SEQ) {
      const float* xq = xp + (tb + 8) * BATCH;
#pragma unroll
      for (int i = 0; i < 8; ++i) xn[i] = *(const float2*)&xq[i * BATCH];
    }

#pragma unroll
    for (int i = 0; i < 8; ++i) {
      const int t = tb + i;

      // --- fold partials of step t-1 (post-bar2 critical path) ---
      const f32x4 q0 = *(const f32x4*)&partial[0][0];
      const f32x4 q1 = *(const f32x4*)&partial[1][0];
      const float f0 = ((q0[0] + q0[1]) + (q0[2] + q0[3])) + b3v;
      const float f1 = ((q1[0] + q1[1]) + (q1[2] + q1[3])) + b3v;

      // h1 pre-activation via precomputed base: pre = base + w11*f
      const float pre0 = __builtin_fmaf(f0, w11, base0);
      const float pre1 = __builtin_fmaf(f1, w11, base1);
      A_lds[j]       = f2bf_rne(tanh_pade(pre0));
      A_lds[LDA + j] = f2bf_rne(tanh_pade(pre1));

      // off-path: y update, output store, next base
      y0 += f0; // DT = 1.0
      y1 += f1;
      if (tid == 0) {
        float2 o{y0, y1};
        *(float2*)&yo[t * BATCH] = o; // ys[t] = pre-update state of step t
      }
      {
        const float xaN0 = (i < 7) ? xa0[i + 1] : xn[0].x * w10 + b1j;
        const float xaN1 = (i < 7) ? xa1[i + 1] : xn[0].y * w10 + b1j;
        base0 = __builtin_fmaf(y0, w11, xaN0);
        base1 = __builtin_fmaf(y1, w11, xaN1);
      }
      __syncthreads(); // bar1: h1 visible

      // --- A-fragments: unconditional vector reads (pad rows -> disjoint banks) ---
      short8 areg[8];
#pragma unroll
      for (int kc = 0; kc < 8; ++kc)
        areg[kc] = *(const short8*)&A_lds[aoff + kc * 32];

      // --- tiles 0,1: K=256 over 8 chunks (2 indep acc chains) ---
      f32x4 acc0, acc1, acc2, acc3;
      {
        const bf16x8 a = __builtin_bit_cast(bf16x8, areg[0]);
        acc0 = __builtin_amdgcn_mfma_f32_16x16x32_bf16(a, __builtin_bit_cast(bf16x8, bf[0][0]), kZero, 0, 0, 0);
        acc1 = __builtin_amdgcn_mfma_f32_16x16x32_bf16(a, __builtin_bit_cast(bf16x8, bf[1][0]), kZero, 0, 0, 0);
      }
#pragma unroll
      for (int kc = 1; kc < 8; ++kc) {
        const bf16x8 a = __builtin_bit_cast(bf16x8, areg[kc]);
        acc0 = __builtin_amdgcn_mfma_f32_16x16x32_bf16(a, __builtin_bit_cast(bf16x8, bf[0][kc]), acc0, 0, 0, 0);
        acc1 = __builtin_amdgcn_mfma_f32_16x16x32_bf16(a, __builtin_bit_cast(bf16x8, bf[1][kc]), acc1, 0, 0, 0);
      }

      // --- s01 on ALL lanes (lanes 32-63 confined garbage);
      //     chain0 in lanes 0-15 reg0, chain1 in lanes 16-31 reg0 ---
      float s01 = tanh_pade(acc0[0] + b2c[0]) * w3c[0] +
                  tanh_pade(acc1[0] + b2c[1]) * w3c[1];

      // --- tiles 2,3 (VALU above slots into this MFMA issue/drain) ---
      {
        const bf16x8 a = __builtin_bit_cast(bf16x8, areg[0]);
        acc2 = __builtin_amdgcn_mfma_f32_16x16x32_bf16(a, __builtin_bit_cast(bf16x8, bf[2][0]), kZero, 0, 0, 0);
        acc3 = __builtin_amdgcn_mfma_f32_16x16x32_bf16(a, __builtin_bit_cast(bf16x8, bf[3][0]), kZero, 0, 0, 0);
      }
#pragma unroll
      for (int kc = 1; kc < 8; ++kc) {
        const bf16x8 a = __builtin_bit_cast(bf16x8, areg[kc]);
        acc2 = __builtin_amdgcn_mfma_f32_16x16x32_bf16(a, __builtin_bit_cast(bf16x8, bf[2][kc]), acc2, 0, 0, 0);
        acc3 = __builtin_amdgcn_mfma_f32_16x16x32_bf16(a, __builtin_bit_cast(bf16x8, bf[3][kc]), acc3, 0, 0, 0);
      }

      const float s23 = tanh_pade(acc2[0] + b2c[2]) * w3c[2] +
                        tanh_pade(acc3[0] + b2c[3]) * w3c[3];

      // --- reduce 16-lane column groups; chain0 -> lane15, chain1 -> lane31 ---
      const float r = row16_sum_to_lane15(s01 + s23);
      if ((lane & 15) == 15 && lane < 32)
        partial[lane >> 4][wave] = r;
      __syncthreads(); // bar2: partials visible (folded at top of next step)
    }

    if (tb + 8 < SEQ) {
#pragma unroll
      for (int i = 0; i < 8; ++i) xb[i] = xn[i];
#pragma unroll
      for (int i = 0; i < 8; ++i) {
        xa0[i] = xb[i].x * w10 + b1j;
        xa1[i] = xb[i].y * w10 + b1j;
      }
    }
  }
}

extern "C" void kernel_launch(void* const* d_in, const int* in_sizes, int n_in,
                              void* d_out, int out_size, void* d_ws, size_t ws_size,
                              hipStream_t stream) {
  const float* x  = (const float*)d_in[0];
  const float* W1 = (const float*)d_in[1];
  const float* b1 = (const float*)d_in[2];
  const float* W2 = (const float*)d_in[3];
  const float* b2 = (const float*)d_in[4];
  const float* W3 = (const float*)d_in[5];
  const float* b3 = (const float*)d_in[6];
  const float* s0 = (const float*)d_in[7];
  unsigned short* ws = (unsigned short*)d_ws; // 65536 bf16 = 128 KB
  float* out = (float*)d_out;

  pack_w2_kernel<<<256, 256, 0, stream>>>(W2, ws);
  odenet_kernel<<<256, 256, 0, stream>>>(x, W1, b1, ws, b2, W3, b3, s0, out);
}